// Round 5
// baseline (121.343 us; speedup 1.0000x reference)
//
#include <hip/hip_runtime.h>
#include <math.h>

// Problem constants
#define BB    16      // batch
#define CC    64      // channels
#define HW    441     // h*w
#define QP    448     // padded to 28 tiles of 16
#define NCLS  10
#define MM    2205
#define MP    2208    // padded to 138 tiles of 16 = 69 pairs
#define NSPLIT 4

typedef _Float16 half8 __attribute__((ext_vector_type(8)));
typedef float   float4_ __attribute__((ext_vector_type(4)));

// sorted top-3 insert (a0>=a1>=a2): 3 ops via med3
__device__ __forceinline__ void ins3(float d, float& a0, float& a1, float& a2) {
    float n0 = fmaxf(d, a0);
    float n1 = __builtin_amdgcn_fmed3f(d, a0, a1);
    float n2 = __builtin_amdgcn_fmed3f(d, a1, a2);
    a0 = n0; a1 = n1; a2 = n2;
}

// merge sorted triple (b0>=b1>=b2) into sorted triple (a0>=a1>=a2): 6 ops
__device__ __forceinline__ void mrg3(float b0, float b1, float b2,
                                     float& a0, float& a1, float& a2) {
    float c0 = fmaxf(a0, b0);
    float c1 = fmaxf(fmaxf(fminf(a0, b0), a1), b1);
    float c2 = fmaxf(__builtin_amdgcn_fmed3f(a0, b1, b2),
                     __builtin_amdgcn_fmed3f(b0, a1, a2));
    a0 = c0; a1 = c1; a2 = c2;
}

// ---- fused prep: normalize queries + supports -> fp16, LINEAR [desc][c] layout,
// LDS-transposed fully-coalesced 4KB block stores ----
__global__ __launch_bounds__(256) void prep(const float* __restrict__ x1,
                                            const float* __restrict__ x2,
                                            _Float16* __restrict__ qn,
                                            _Float16* __restrict__ sn) {
    __shared__ float ssred[256];
    __shared__ half8 obuf[256];     // 32 descriptors x 8 pieces = 4KB
    int tid = threadIdx.x;
    int ml = tid & 31, cg = tid >> 5;     // 32 descriptors x 8 c-groups
    float v[8];
    half8* dstblk;
    if (blockIdx.x < BB * 14) {           // queries: 16 b x 14 p-tiles of 32
        int b = blockIdx.x / 14, pt = blockIdx.x % 14;
        int p = pt * 32 + ml;
        const float* src = x1 + (size_t)b * CC * HW + p;
        bool real = p < HW;
        #pragma unroll
        for (int i = 0; i < 8; ++i) v[i] = real ? src[(size_t)(cg * 8 + i) * HW] : 0.f;
        dstblk = (half8*)(qn + ((size_t)(b * QP + pt * 32)) * CC);
    } else {                              // supports: 10 n x 69 m-tiles of 32
        int sb = blockIdx.x - BB * 14;
        int n = sb / 69, mt = sb % 69;
        int m = mt * 32 + ml;
        const float* src = x2 + (size_t)n * CC * MM + m;
        bool real = m < MM;
        #pragma unroll
        for (int i = 0; i < 8; ++i) v[i] = real ? src[(size_t)(cg * 8 + i) * MM] : 0.f;
        dstblk = (half8*)(sn + ((size_t)(n * MP + mt * 32)) * CC);
    }
    float ss = 0.f;
    #pragma unroll
    for (int i = 0; i < 8; ++i) ss += v[i] * v[i];
    ssred[tid] = ss;
    __syncthreads();
    float tot = 0.f;
    #pragma unroll
    for (int j = 0; j < 8; ++j) tot += ssred[j * 32 + ml];
    float inv = 1.f / fmaxf(sqrtf(tot), 1e-12f);
    half8 h;
    #pragma unroll
    for (int i = 0; i < 8; ++i) h[i] = (_Float16)(v[i] * inv);
    obuf[ml * 8 + cg] = h;
    __syncthreads();
    dstblk[tid] = obuf[tid];              // 256 x 16B contiguous
}

// ---- main: 1-wave blocks, 7 q-tiles/wave in regs, B streamed global->VGPR,
// no LDS, no barriers; software prefetch one pair ahead ----
__global__ __launch_bounds__(64, 2) void img2class_mfma(const _Float16* __restrict__ qn,
                                                        const _Float16* __restrict__ sn,
                                                        float* __restrict__ partial) {
    int blk = blockIdx.x;
    int ms = blk & 3;            // m-split 0..3
    int qw = (blk >> 2) & 3;     // q-group 0..3 (7 q-tiles each)
    int bn = blk >> 4;           // 0..159
    int b = bn / NCLS, n = bn % NCLS;
    int lane = threadIdx.x;
    int col = lane & 15, quad = lane >> 4;

    const int P0[4] = {0, 18, 35, 52};
    const int P1[4] = {18, 35, 52, 69};
    int p0 = P0[ms], p1 = P1[ms];

    // A fragments for 7 q-tiles: A[m=col][k=quad*8+j], k-halves 0/1
    half8 A0[7], A1[7];
    const _Float16* abase = qn + ((size_t)(b * QP + qw * 112 + col)) * CC + quad * 8;
    #pragma unroll
    for (int qt = 0; qt < 7; ++qt) {
        A0[qt] = *(const half8*)(abase + qt * 16 * CC);
        A1[qt] = *(const half8*)(abase + qt * 16 * CC + 32);
    }

    float t0[7][4], t1[7][4], t2[7][4];
    #pragma unroll
    for (int qt = 0; qt < 7; ++qt)
        #pragma unroll
        for (int r = 0; r < 4; ++r) { t0[qt][r] = -1.0e30f; t1[qt][r] = -1.0e30f; t2[qt][r] = -1.0e30f; }

    // tile 137 (odd tile of pair 68): real m only for col < 13
    float pen = (col >= 13) ? -1.0e30f : 0.0f;

    // B fragment base: lane reads support row (tile*16+col), piece quad (+4 for k-half 1)
    const _Float16* bbase = sn + ((size_t)(n * MP + col)) * CC + quad * 8;

    const half8* cb = (const half8*)(bbase + (size_t)(2 * p0) * 16 * CC);
    half8 C0e = cb[0], C1e = cb[4];        // even tile, k 0-31 / 32-63
    half8 C0o = cb[128], C1o = cb[132];    // odd tile (+16*CC halves = 128 half8)

    for (int p = p0; p < p1; ++p) {
        int pnext = (p + 1 < p1) ? (p + 1) : p0;   // last iter: dummy reload
        const half8* nb = (const half8*)(bbase + (size_t)(2 * pnext) * 16 * CC);
        half8 N0e = nb[0], N1e = nb[4], N0o = nb[128], N1o = nb[132];

        bool lastpen = (p == 68);
        #pragma unroll
        for (int qt = 0; qt < 7; ++qt) {
            float4_ z = {0.f, 0.f, 0.f, 0.f};
            float4_ ae = __builtin_amdgcn_mfma_f32_16x16x32_f16(A0[qt], C0e, z, 0, 0, 0);
            ae = __builtin_amdgcn_mfma_f32_16x16x32_f16(A1[qt], C1e, ae, 0, 0, 0);
            float4_ ao = __builtin_amdgcn_mfma_f32_16x16x32_f16(A0[qt], C0o, z, 0, 0, 0);
            ao = __builtin_amdgcn_mfma_f32_16x16x32_f16(A1[qt], C1o, ao, 0, 0, 0);
            if (lastpen) { ao.x += pen; ao.y += pen; ao.z += pen; ao.w += pen; }
            ins3(fmaxf(ae.x, ao.x), t0[qt][0], t1[qt][0], t2[qt][0]);
            ins3(fmaxf(ae.y, ao.y), t0[qt][1], t1[qt][1], t2[qt][1]);
            ins3(fmaxf(ae.z, ao.z), t0[qt][2], t1[qt][2], t2[qt][2]);
            ins3(fmaxf(ae.w, ao.w), t0[qt][3], t1[qt][3], t2[qt][3]);
        }
        C0e = N0e; C1e = N1e; C0o = N0o; C1o = N1o;
    }

    // merge top-3 across the 16 m-columns (butterfly within 16-lane groups)
    #pragma unroll
    for (int qt = 0; qt < 7; ++qt) {
        #pragma unroll
        for (int s = 1; s <= 8; s <<= 1) {
            #pragma unroll
            for (int r = 0; r < 4; ++r) {
                float b0 = __shfl_xor(t0[qt][r], s);
                float b1 = __shfl_xor(t1[qt][r], s);
                float b2 = __shfl_xor(t2[qt][r], s);
                mrg3(b0, b1, b2, t0[qt][r], t1[qt][r], t2[qt][r]);
            }
        }
    }

    // per-query partial sorted triple: partial[(bn*4+ms)*QP + q]*3
    if (col == 0) {
        float* pp = partial + ((size_t)(bn * NSPLIT + ms) * QP + qw * 112 + quad * 4) * 3;
        #pragma unroll
        for (int qt = 0; qt < 7; ++qt) {
            #pragma unroll
            for (int r = 0; r < 4; ++r) {
                pp[(qt * 16 + r) * 3 + 0] = t0[qt][r];
                pp[(qt * 16 + r) * 3 + 1] = t1[qt][r];
                pp[(qt * 16 + r) * 3 + 2] = t2[qt][r];
            }
        }
    }
}

// ---- merge 4 m-splits per query, sum top-3, reduce over queries ----
__global__ __launch_bounds__(512) void merge_splits(const float* __restrict__ partial,
                                                    float* __restrict__ out) {
    __shared__ float red[512];
    int bn = blockIdx.x;
    int q  = threadIdx.x;
    float s = 0.f;
    if (q < HW) {
        const float* p = partial + ((size_t)(bn * NSPLIT) * QP + q) * 3;
        float a0 = p[0], a1 = p[1], a2 = p[2];
        #pragma unroll
        for (int sp = 1; sp < NSPLIT; ++sp) {
            const float* ps = p + (size_t)sp * QP * 3;
            mrg3(ps[0], ps[1], ps[2], a0, a1, a2);
        }
        s = a0 + a1 + a2;
    }
    red[q] = s;
    __syncthreads();
    #pragma unroll
    for (int stride = 256; stride >= 1; stride >>= 1) {
        if (q < stride) red[q] += red[q + stride];
        __syncthreads();
    }
    if (q == 0) out[bn] = red[0];
}

extern "C" void kernel_launch(void* const* d_in, const int* in_sizes, int n_in,
                              void* d_out, int out_size, void* d_ws, size_t ws_size,
                              hipStream_t stream) {
    const float* x1 = (const float*)d_in[0];   // [16,64,21,21]
    const float* x2 = (const float*)d_in[1];   // [10,64,2205]
    float* out = (float*)d_out;                // [16,10]

    _Float16* qn   = (_Float16*)d_ws;                  // 16*448*64 halves
    _Float16* sn   = qn + (size_t)BB * QP * CC;        // 10*2208*64 halves (linear)
    float* partial = (float*)(sn + (size_t)NCLS * MP * CC);  // 160*4*448*3 floats

    prep<<<BB * 14 + NCLS * 69, 256, 0, stream>>>(x1, x2, qn, sn);
    img2class_mfma<<<BB * NCLS * 4 * NSPLIT, 64, 0, stream>>>(qn, sn, partial);
    merge_splits<<<BB * NCLS, 512, 0, stream>>>(partial, out);
}